// Round 1
// baseline (29.986 us; speedup 1.0000x reference)
//
#include <hip/hip_runtime.h>
#include <hip/hip_bf16.h>

// out[i] = verified_id[i*ndt + accept_lens[i] - 1], i in [0, BS)
// Memory-bound gather. 4 rows per thread: int4 lens load + float4 out store
// (both perfectly coalesced); the verified_id reads are strided-by-32B
// scalar dword loads (unavoidable — the gathered element position is
// data-dependent within each 8-float row).
__global__ void Model_28681791602777_kernel(const float* __restrict__ vid,
                                            const int* __restrict__ lens,
                                            const int* __restrict__ ndt_ptr,
                                            float* __restrict__ out,
                                            int bs) {
    const int ndt = ndt_ptr[0];           // scalar broadcast (1-elem input)
    const int n4 = bs >> 2;               // groups of 4 rows
    const int stride = gridDim.x * blockDim.x;
    int t = blockIdx.x * blockDim.x + threadIdx.x;

    const int4* lens4 = reinterpret_cast<const int4*>(lens);
    float4* out4 = reinterpret_cast<float4*>(out);

    for (; t < n4; t += stride) {
        int4 l = lens4[t];
        const int base = t << 2;
        float4 o;
        o.x = vid[(base + 0) * ndt + l.x - 1];
        o.y = vid[(base + 1) * ndt + l.y - 1];
        o.z = vid[(base + 2) * ndt + l.z - 1];
        o.w = vid[(base + 3) * ndt + l.w - 1];
        out4[t] = o;
    }

    // tail (bs not divisible by 4) — handled by first thread only
    if (blockIdx.x == 0 && threadIdx.x == 0) {
        for (int r = n4 << 2; r < bs; ++r)
            out[r] = vid[r * ndt + lens[r] - 1];
    }
}

extern "C" void kernel_launch(void* const* d_in, const int* in_sizes, int n_in,
                              void* d_out, int out_size, void* d_ws, size_t ws_size,
                              hipStream_t stream) {
    const float* vid = (const float*)d_in[0];   // verified_id, BS*NDT f32
    const int* lens  = (const int*)d_in[1];     // accept_lens, BS i32
    const int* ndt   = (const int*)d_in[2];     // num_draft_tokens, 1 i32
    float* out = (float*)d_out;                 // BS f32

    const int bs = in_sizes[1];
    const int n4 = bs >> 2;

    const int block = 256;
    int grid = (n4 + block - 1) / block;
    if (grid > 2048) grid = 2048;               // grid-stride the rest
    if (grid < 1) grid = 1;

    Model_28681791602777_kernel<<<grid, block, 0, stream>>>(vid, lens, ndt, out, bs);
}